// Round 6
// baseline (87.630 us; speedup 1.0000x reference)
//
#include <hip/hip_runtime.h>
#include <math.h>

// Problem constants
#define B_  2
#define S_  2048
#define D_  512
#define H_  8
#define DK_ 64
#define M_  (B_*S_)        // 4096
#define NW   (D_*D_)       // 262144 elems per weight

// q scale: 1/sqrt(DK) * log2(e), so softmax exp(x) becomes exp2(score*sph)
#define QSCALE 0.1803368801111214f

typedef __attribute__((ext_vector_type(8))) short bf16x8;
typedef __attribute__((ext_vector_type(4))) float f32x4;
typedef __attribute__((ext_vector_type(2))) unsigned int u32x2;

__device__ inline unsigned short f2bf(float f) {
    union { float f; unsigned int u; } a; a.f = f;
    unsigned int u = a.u;
    u += 0x7FFFu + ((u >> 16) & 1u);   // RNE
    return (unsigned short)(u >> 16);
}

// packed f32x2 -> bf16x2 (RNE), low word = lo
__device__ inline unsigned int cvtpk(float lo, float hi) {
    unsigned int r;
    asm("v_cvt_pk_bf16_f32 %0, %1, %2" : "=v"(r) : "v"(lo), "v"(hi));
    return r;
}

// async global->LDS, 16B per lane. LDS dest must be linear in lane id.
#define GLL(g, l) __builtin_amdgcn_global_load_lds( \
    (const __attribute__((address_space(1))) unsigned int*)(g), \
    (__attribute__((address_space(3))) unsigned int*)(l), 16, 0, 0)

__device__ inline void cvt8(const float* s, unsigned short* d) {
    const float4* sp = (const float4*)s;
    float4 v0 = sp[0], v1 = sp[1];
    union { bf16x8 v; unsigned short s[8]; } u;
    u.s[0]=f2bf(v0.x); u.s[1]=f2bf(v0.y); u.s[2]=f2bf(v0.z); u.s[3]=f2bf(v0.w);
    u.s[4]=f2bf(v1.x); u.s[5]=f2bf(v1.y); u.s[6]=f2bf(v1.z); u.s[7]=f2bf(v1.w);
    *(bf16x8*)d = u.v;
}

__device__ inline void cvtw8(unsigned short* d, float4 v0, float4 v1) {
    union { bf16x8 v; unsigned short s[8]; } u;
    u.s[0]=f2bf(v0.x); u.s[1]=f2bf(v0.y); u.s[2]=f2bf(v0.z); u.s[3]=f2bf(v0.w);
    u.s[4]=f2bf(v1.x); u.s[5]=f2bf(v1.y); u.s[6]=f2bf(v1.z); u.s[7]=f2bf(v1.w);
    *(bf16x8*)d = u.v;
}

// ---------------------------------------------------------------------------
// fp32 -> bf16 for the 4 weight matrices only (A-conversion fused into GEMM).
// ---------------------------------------------------------------------------
__global__ __launch_bounds__(256) void cvtw_kernel(
    const float* __restrict__ wq, const float* __restrict__ wk,
    const float* __restrict__ wv, const float* __restrict__ wo,
    unsigned short* __restrict__ WB)
{
    int e = (blockIdx.x * 256 + threadIdx.x) * 8;   // 0 .. 4*NW
    int wi = e >> 18;              // NW = 2^18
    int off = e & (NW - 1);
    const float* src = wi == 0 ? wq : wi == 1 ? wk : wi == 2 ? wv : wo;
    cvt8(src + off, WB + e);
}

// ---------------------------------------------------------------------------
// Fused Q/K/V projection GEMM. A is fp32 (reg-staged, converted in-kernel,
// 2-deep load pipeline); W is bf16 via global_load_lds. Double-buffered,
// 1 barrier/iter. Grid (192, 8): blockIdx.x = seg*64 + row-tile.
// ---------------------------------------------------------------------------
__global__ __launch_bounds__(256) void qkv_gemm(
    const float* __restrict__ qF, const float* __restrict__ kF,
    const float* __restrict__ vF, const unsigned short* __restrict__ WB,
    const float* __restrict__ bq, const float* __restrict__ bk, const float* __restrict__ bv,
    unsigned short* __restrict__ q_ws, unsigned short* __restrict__ k_ws,
    unsigned short* __restrict__ vT_ws)
{
    __shared__ unsigned short A_lds[2][64][32];
    __shared__ unsigned short B_lds[2][64][32];

    const int t    = threadIdx.x;
    const int lane = t & 63;
    const int wave = t >> 6;
    const int wm   = wave >> 1, wn = wave & 1;
    const int lrow = lane & 15, lgr = lane >> 4;
    const int seg  = blockIdx.x >> 6;
    const int bm   = blockIdx.x & 63;
    const int bn   = blockIdx.y;

    const float*          A    = seg == 0 ? qF : seg == 1 ? kF : vF;
    const unsigned short* W    = WB + (size_t)seg * NW;
    const float*          bias = seg == 0 ? bq : seg == 1 ? bk : bv;
    unsigned short*       Cp   = seg == 0 ? q_ws : seg == 1 ? k_ws : vT_ws;

    f32x4 acc[2][2] = {};

    const float* Agp = A + (size_t)(bm*64 + (t>>2))*512 + (t&3)*8;
    const unsigned short* Wg = W + (size_t)(bn*64 + (t>>2))*512 + (t&3)*8;
    unsigned short* lA0 = &A_lds[0][t>>2][(t&3)*8];
    unsigned short* lA1 = &A_lds[1][t>>2][(t&3)*8];
    unsigned short* lB0 = &B_lds[0][t>>2][(t&3)*8];
    unsigned short* lB1 = &B_lds[1][t>>2][(t&3)*8];

    // prologue: tile 0 staged, tile 1 loads in flight
    float4 a0n = *(const float4*)(Agp);
    float4 a1n = *(const float4*)(Agp + 4);
    GLL(Wg, lB0);
    cvtw8(lA0, a0n, a1n);                       // tile 0 -> buf 0
    a0n = *(const float4*)(Agp + 32);           // tile 1 issue
    a1n = *(const float4*)(Agp + 36);

    #pragma unroll
    for (int i = 0; i < 16; ++i) {
        __syncthreads();                        // tile i (A ds_write + W GLL) visible
        const int buf = i & 1;
        if (i < 15) {
            GLL(Wg + (i+1)*32, buf ? lB0 : lB1);
            cvtw8(buf ? lA0 : lA1, a0n, a1n);   // tile i+1 -> buf^1
        }
        if (i < 14) {
            a0n = *(const float4*)(Agp + (i+2)*32);
            a1n = *(const float4*)(Agp + (i+2)*32 + 4);
        }

        bf16x8 a0 = *(const bf16x8*)&A_lds[buf][wm*32 +      lrow][lgr*8];
        bf16x8 a1 = *(const bf16x8*)&A_lds[buf][wm*32 + 16 + lrow][lgr*8];
        bf16x8 b0 = *(const bf16x8*)&B_lds[buf][wn*32 +      lrow][lgr*8];
        bf16x8 b1 = *(const bf16x8*)&B_lds[buf][wn*32 + 16 + lrow][lgr*8];

        acc[0][0] = __builtin_amdgcn_mfma_f32_16x16x32_bf16(a0, b0, acc[0][0], 0, 0, 0);
        acc[0][1] = __builtin_amdgcn_mfma_f32_16x16x32_bf16(a0, b1, acc[0][1], 0, 0, 0);
        acc[1][0] = __builtin_amdgcn_mfma_f32_16x16x32_bf16(a1, b0, acc[1][0], 0, 0, 0);
        acc[1][1] = __builtin_amdgcn_mfma_f32_16x16x32_bf16(a1, b1, acc[1][1], 0, 0, 0);
    }

    #pragma unroll
    for (int mf = 0; mf < 2; ++mf)
    #pragma unroll
    for (int nf = 0; nf < 2; ++nf)
    #pragma unroll
    for (int r = 0; r < 4; ++r) {
        int grow = bm*64 + wm*32 + mf*16 + lgr*4 + r;
        int gcol = bn*64 + wn*32 + nf*16 + lrow;
        float v = acc[mf][nf][r] + bias[gcol];
        if (seg == 0) v *= QSCALE;
        int bb = grow >> 11, s = grow & 2047;
        int hh = gcol >> 6,  dk = gcol & 63;
        unsigned short bv16 = f2bf(v);
        if (seg < 2)
            Cp[((size_t)(bb*H_ + hh)*S_ + s)*DK_ + dk] = bv16;
        else
            Cp[((size_t)(bb*H_ + hh)*DK_ + dk)*S_ + s] = bv16;
    }
}

// ---------------------------------------------------------------------------
// Output projection GEMM: fp32 out = attn(bf16) @ Wo^T + bo. GLL dbuf.
// ---------------------------------------------------------------------------
__global__ __launch_bounds__(256) void out_gemm(
    const unsigned short* __restrict__ A,
    const unsigned short* __restrict__ W,
    const float* __restrict__ bias,
    float* __restrict__ C)
{
    __shared__ unsigned short A_lds[2][64][32];
    __shared__ unsigned short B_lds[2][64][32];

    const int t    = threadIdx.x;
    const int lane = t & 63;
    const int wave = t >> 6;
    const int wm   = wave >> 1, wn = wave & 1;
    const int lrow = lane & 15, lgr = lane >> 4;
    const int bm   = blockIdx.x, bn = blockIdx.y;

    f32x4 acc[2][2] = {};

    const unsigned short* Ag = A + (size_t)(bm*64 + (t>>2))*512 + (t&3)*8;
    const unsigned short* Wg = W + (size_t)(bn*64 + (t>>2))*512 + (t&3)*8;
    unsigned short* lA0 = &A_lds[0][t>>2][(t&3)*8];
    unsigned short* lA1 = &A_lds[1][t>>2][(t&3)*8];
    unsigned short* lB0 = &B_lds[0][t>>2][(t&3)*8];
    unsigned short* lB1 = &B_lds[1][t>>2][(t&3)*8];

    GLL(Ag, lA0);
    GLL(Wg, lB0);

    for (int kk = 0; kk < 512; kk += 32) {
        const int buf = (kk >> 5) & 1;
        __syncthreads();
        if (kk < 480) {
            GLL(Ag + kk + 32, buf ? lA0 : lA1);
            GLL(Wg + kk + 32, buf ? lB0 : lB1);
        }

        bf16x8 a0 = *(const bf16x8*)&A_lds[buf][wm*32 +      lrow][lgr*8];
        bf16x8 a1 = *(const bf16x8*)&A_lds[buf][wm*32 + 16 + lrow][lgr*8];
        bf16x8 b0 = *(const bf16x8*)&B_lds[buf][wn*32 +      lrow][lgr*8];
        bf16x8 b1 = *(const bf16x8*)&B_lds[buf][wn*32 + 16 + lrow][lgr*8];

        acc[0][0] = __builtin_amdgcn_mfma_f32_16x16x32_bf16(a0, b0, acc[0][0], 0, 0, 0);
        acc[0][1] = __builtin_amdgcn_mfma_f32_16x16x32_bf16(a0, b1, acc[0][1], 0, 0, 0);
        acc[1][0] = __builtin_amdgcn_mfma_f32_16x16x32_bf16(a1, b0, acc[1][0], 0, 0, 0);
        acc[1][1] = __builtin_amdgcn_mfma_f32_16x16x32_bf16(a1, b1, acc[1][1], 0, 0, 0);
    }

    #pragma unroll
    for (int mf = 0; mf < 2; ++mf)
    #pragma unroll
    for (int nf = 0; nf < 2; ++nf)
    #pragma unroll
    for (int r = 0; r < 4; ++r) {
        int grow = bm*64 + wm*32 + mf*16 + lgr*4 + r;
        int gcol = bn*64 + wn*32 + nf*16 + lrow;
        C[(size_t)grow*512 + gcol] = acc[mf][nf][r] + bias[gcol];
    }
}

// ---------------------------------------------------------------------------
// Attention with SWAPPED QK^T: sc = mfma(K, Q) puts scores transposed so each
// lane's 16 values share one q-row (q = lane&15). Gains: float4 sph loads,
// scalar psum/linv, packed b64 P writes. PV computes O^T = mfma(V^T, P^T).
// No-max softmax via exp2 (log2e folded into Q scale). Split-K across wave
// halves, 512 threads = 8 waves, pad-68 LDS. No setprio (lockstep waves).
// ---------------------------------------------------------------------------
__global__ __launch_bounds__(512, 4) void attn_fast(
    const unsigned short* __restrict__ q_ws,
    const unsigned short* __restrict__ k_ws,
    const unsigned short* __restrict__ vT_ws,
    const float* __restrict__ sph,
    unsigned short* __restrict__ attn_ws)
{
    __shared__ unsigned short K_lds[2][64][68];
    __shared__ unsigned short V_lds[2][64][68];
    __shared__ unsigned short P_lds[8][16][68];   // [wave][q][k]
    __shared__ float l_sh[8][16];
    // O_sh overlays K_lds (dead after main loop): 4*64*17*4 = 17408 = sizeof(K_lds)
    float (*O_sh)[64][17] = (float (*)[64][17])(&K_lds[0][0][0]);

    const int t    = threadIdx.x;
    const int lane = t & 63, wave = t >> 6;
    const int lrow = lane & 15, lgr = lane >> 4;
    const int wq = wave & 3;      // q sub-tile (16 rows)
    const int wh = wave >> 2;     // k half
    const int qt = blockIdx.x, bh = blockIdx.y;
    const int b  = bh >> 3;
    const int h  = bh & 7;
    const int qbase = qt * 64;
    const size_t head_off = (size_t)bh * S_ * DK_;

    // Q B-frags (col j = q = lane&15): same addresses as the A-frag load
    bf16x8 qf0, qf1;
    {
        const unsigned short* qp =
            q_ws + head_off + (size_t)(qbase + wq*16 + lrow)*DK_ + lgr*8;
        qf0 = *(const bf16x8*)qp;
        qf1 = *(const bf16x8*)(qp + 32);
    }

    const int sh = t >> 8;
    const int sr = (t >> 2) & 63;
    const int sc = (t & 3) * 16;
    const unsigned short* kstage = k_ws  + head_off + ((size_t)sh*1024 + sr)*DK_ + sc;
    const unsigned short* vstage = vT_ws + head_off + (size_t)sr*S_ + sh*1024 + sc;

    // per-lane sph row pointer: q = qbase + wq*16 + lrow (fixed per lane)
    const float* sph_q = sph + (size_t)b*S_*S_
                       + (size_t)(qbase + wq*16 + lrow)*S_ + wh*1024 + lgr*4;

    f32x4 acc_o[4] = {};          // O^T: col = q = lane&15, row = d
    float psum = 0.f;             // row-sum partial for q = lane&15

    // prologue: stage tile 0 + sph tile 0
    bf16x8 kr0 = *(const bf16x8*)(kstage);
    bf16x8 kr1 = *(const bf16x8*)(kstage + 8);
    bf16x8 vr0 = *(const bf16x8*)(vstage);
    bf16x8 vr1 = *(const bf16x8*)(vstage + 8);
    *(bf16x8*)&K_lds[sh][sr][sc]     = kr0;
    *(bf16x8*)&K_lds[sh][sr][sc + 8] = kr1;
    *(bf16x8*)&V_lds[sh][sr][sc]     = vr0;
    *(bf16x8*)&V_lds[sh][sr][sc + 8] = vr1;

    float4 sphr[4];
    #pragma unroll
    for (int nf = 0; nf < 4; ++nf)
        sphr[nf] = *(const float4*)(sph_q + nf*16);

    for (int kt = 0; kt < 16; ++kt) {
        __syncthreads();   // LDS tile kt ready

        if (kt < 15) {     // next-tile K/V register prefetch
            const unsigned short* kp = kstage + (size_t)(kt+1)*64*DK_;
            const unsigned short* vp = vstage + (kt+1)*64;
            kr0 = *(const bf16x8*)(kp);
            kr1 = *(const bf16x8*)(kp + 8);
            vr0 = *(const bf16x8*)(vp);
            vr1 = *(const bf16x8*)(vp + 8);
        }

        // swapped QK^T: sc4[nf] = S^T[k = nf*16 + lgr*4 + r][q = lrow]
        f32x4 sc4[4];
        #pragma unroll
        for (int nf = 0; nf < 4; ++nf) {
            bf16x8 kf0 = *(const bf16x8*)&K_lds[wh][nf*16 + lrow][lgr*8];
            bf16x8 kf1 = *(const bf16x8*)&K_lds[wh][nf*16 + lrow][32 + lgr*8];
            f32x4 a = {};
            a = __builtin_amdgcn_mfma_f32_16x16x32_bf16(kf0, qf0, a, 0, 0, 0);
            a = __builtin_amdgcn_mfma_f32_16x16x32_bf16(kf1, qf1, a, 0, 0, 0);
            sc4[nf] = a;
        }

        // p = exp2(s*sph); scalar psum; pack pairs -> P_lds[q][k] (b64 writes)
        #pragma unroll
        for (int nf = 0; nf < 4; ++nf) {
            float4 sv = sphr[nf];
            float p0 = __builtin_amdgcn_exp2f(sc4[nf][0] * sv.x);
            float p1 = __builtin_amdgcn_exp2f(sc4[nf][1] * sv.y);
            float p2 = __builtin_amdgcn_exp2f(sc4[nf][2] * sv.z);
            float p3 = __builtin_amdgcn_exp2f(sc4[nf][3] * sv.w);
            psum += (p0 + p1) + (p2 + p3);
            u32x2 w;
            w.x = cvtpk(p0, p1);
            w.y = cvtpk(p2, p3);
            *(u32x2*)&P_lds[wave][lrow][nf*16 + lgr*4] = w;
        }

        if (kt < 15) {     // next-tile sph prefetch (float4, hides under PV)
            #pragma unroll
            for (int nf = 0; nf < 4; ++nf)
                sphr[nf] = *(const float4*)(sph_q + (kt+1)*64 + nf*16);
        }

        // PV: O^T[d][q] += V^T[d][k] * P^T[k][q]  -> acc_o[nb] = mfma(vf, pb)
        #pragma unroll
        for (int ks2 = 0; ks2 < 2; ++ks2) {
            bf16x8 pb = *(const bf16x8*)&P_lds[wave][lrow][ks2*32 + lgr*8];
            #pragma unroll
            for (int nb = 0; nb < 4; ++nb) {
                bf16x8 vf = *(const bf16x8*)&V_lds[wh][nb*16 + lrow][ks2*32 + lgr*8];
                acc_o[nb] = __builtin_amdgcn_mfma_f32_16x16x32_bf16(vf, pb, acc_o[nb], 0, 0, 0);
            }
        }
        __syncthreads();   // all K/V_lds reads done

        if (kt < 15) {
            *(bf16x8*)&K_lds[sh][sr][sc]     = kr0;
            *(bf16x8*)&K_lds[sh][sr][sc + 8] = kr1;
            *(bf16x8*)&V_lds[sh][sr][sc]     = vr0;
            *(bf16x8*)&V_lds[sh][sr][sc + 8] = vr1;
        }
    }

    // row-sum: reduce over the 4 lgr groups (k-partials), q = lrow
    psum += __shfl_xor(psum, 16, 64);
    psum += __shfl_xor(psum, 32, 64);
    if (lgr == 0)
        l_sh[wave][lrow] = psum;
    __syncthreads();

    const float linv = 1.f / (l_sh[wq][lrow] + l_sh[wq + 4][lrow]);

    if (wh == 1) {
        #pragma unroll
        for (int nb = 0; nb < 4; ++nb)
        #pragma unroll
        for (int r = 0; r < 4; ++r)
            O_sh[wq][nb*16 + lgr*4 + r][lrow] = acc_o[nb][r];
    }
    __syncthreads();
    if (wh == 0) {
        const int q = qbase + wq*16 + lrow;
        unsigned short* op = attn_ws + ((size_t)(b*S_) + q)*D_ + h*64;
        #pragma unroll
        for (int nb = 0; nb < 4; ++nb) {
            float o0 = (acc_o[nb][0] + O_sh[wq][nb*16 + lgr*4 + 0][lrow]) * linv;
            float o1 = (acc_o[nb][1] + O_sh[wq][nb*16 + lgr*4 + 1][lrow]) * linv;
            float o2 = (acc_o[nb][2] + O_sh[wq][nb*16 + lgr*4 + 2][lrow]) * linv;
            float o3 = (acc_o[nb][3] + O_sh[wq][nb*16 + lgr*4 + 3][lrow]) * linv;
            u32x2 w;
            w.x = cvtpk(o0, o1);
            w.y = cvtpk(o2, o3);
            *(u32x2*)(op + nb*16 + lgr*4) = w;
        }
    }
}

// ===========================================================================
// Fallback path (proven): used only if ws_size < 18 MiB.
// ===========================================================================
template<int A_BF16, int MODE>
__global__ __launch_bounds__(256) void gemm_old(
    const void* __restrict__ Aptr,
    const float* __restrict__ W,
    const float* __restrict__ bias,
    void* __restrict__ Cptr)
{
    __shared__ unsigned short A_lds[64][40];
    __shared__ unsigned short B_lds[64][40];

    const int t    = threadIdx.x;
    const int lane = t & 63;
    const int wave = t >> 6;
    const int wm   = wave >> 1, wn = wave & 1;
    const int lrow = lane & 15, lgr = lane >> 4;
    const int bm   = blockIdx.x, bn = blockIdx.y;

    f32x4 acc[2][2] = {};
    const int srow = t >> 2;
    const int scol = (t & 3) * 8;

    for (int kk = 0; kk < 512; kk += 32) {
        if (A_BF16) {
            const unsigned short* A = (const unsigned short*)Aptr;
            bf16x8 v = *(const bf16x8*)(A + (size_t)(bm*64 + srow)*512 + kk + scol);
            *(bf16x8*)&A_lds[srow][scol] = v;
        } else {
            const float* A = (const float*)Aptr;
            cvt8(A + (size_t)(bm*64 + srow)*512 + kk + scol, &A_lds[srow][scol]);
        }
        cvt8(W + (size_t)(bn*64 + srow)*512 + kk + scol, &B_lds[srow][scol]);
        __syncthreads();

        bf16x8 a0 = *(const bf16x8*)&A_lds[wm*32 +      lrow][lgr*8];
        bf16x8 a1 = *(const bf16x8*)&A_lds[wm*32 + 16 + lrow][lgr*8];
        bf16x8 b0 = *(const bf16x8*)&B_lds[wn*32 +      lrow][lgr*8];
        bf16x8 b1 = *(const bf16x8*)&B_lds[wn*32 + 16 + lrow][lgr*8];

        acc[0][0] = __builtin_amdgcn_mfma_f32_16x16x32_bf16(a0, b0, acc[0][0], 0, 0, 0);
        acc[0][1] = __builtin_amdgcn_mfma_f32_16x16x32_bf16(a0, b1, acc[0][1], 0, 0, 0);
        acc[1][0] = __builtin_amdgcn_mfma_f32_16x16x32_bf16(a1, b0, acc[1][0], 0, 0, 0);
        acc[1][1] = __builtin_amdgcn_mfma_f32_16x16x32_bf16(a1, b1, acc[1][1], 0, 0, 0);
        __syncthreads();
    }

    #pragma unroll
    for (int mf = 0; mf < 2; ++mf)
    #pragma unroll
    for (int nf = 0; nf < 2; ++nf)
    #pragma unroll
    for (int r = 0; r < 4; ++r) {
        int grow = bm*64 + wm*32 + mf*16 + lgr*4 + r;
        int gcol = bn*64 + wn*32 + nf*16 + lrow;
        float v = acc[mf][nf][r] + bias[gcol];
        if (MODE == 2) {
            ((float*)Cptr)[(size_t)grow*512 + gcol] = v;
        } else {
            int bb = grow >> 11, s = grow & 2047;
            int hh = gcol >> 6,  dk = gcol & 63;
            unsigned short bv = f2bf(v);
            if (MODE == 0)
                ((unsigned short*)Cptr)[((size_t)(bb*H_ + hh)*S_ + s)*DK_ + dk] = bv;
            else
                ((unsigned short*)Cptr)[((size_t)(bb*H_ + hh)*DK_ + dk)*S_ + s] = bv;
        }
    }
}

__global__ __launch_bounds__(512, 4) void attn_old(
    const unsigned short* __restrict__ q_ws,
    const unsigned short* __restrict__ k_ws,
    const unsigned short* __restrict__ vT_ws,
    const float* __restrict__ sph,
    unsigned short* __restrict__ attn_ws)
{
    __shared__ unsigned short K_lds[2][64][72];
    __shared__ unsigned short V_lds[2][64][72];
    __shared__ unsigned short P_lds[8][16][72];
    __shared__ float m_sh[8][16];
    __shared__ float l_sh[8][16];
    __shared__ float O_sh[4][16][68];

    const int t    = threadIdx.x;
    const int lane = t & 63, wave = t >> 6;
    const int lrow = lane & 15, lgr = lane >> 4;
    const int wq = wave & 3;
    const int wh = wave >> 2;
    const int qt = blockIdx.x, bh = blockIdx.y;
    const int b  = bh >> 3;
    const int h  = bh & 7;
    const int qbase = qt * 64;
    const size_t head_off = (size_t)bh * S_ * DK_;

    bf16x8 qf0, qf1;
    {
        const unsigned short* qp =
            q_ws + head_off + (size_t)(qbase + wq*16 + lrow)*DK_ + lgr*8;
        qf0 = *(const bf16x8*)qp;
        qf1 = *(const bf16x8*)(qp + 32);
    }

    const int sh = t >> 8;
    const int sr = (t >> 2) & 63;
    const int sc = (t & 3) * 16;
    const unsigned short* kstage = k_ws  + head_off + ((size_t)sh*1024 + sr)*DK_ + sc;
    const unsigned short* vstage = vT_ws + head_off + (size_t)sr*S_ + sh*1024 + sc;

    const float* sphb   = sph + (size_t)b * S_ * S_;
    const float* sph_p0 = sphb + (size_t)(qbase + wq*16 + lgr*4 + 0)*S_ + wh*1024 + lrow;
    const float* sph_p1 = sph_p0 + S_;
    const float* sph_p2 = sph_p0 + 2*S_;
    const float* sph_p3 = sph_p0 + 3*S_;

    f32x4 acc_o[4] = {};
    float m_run[4] = {-INFINITY,-INFINITY,-INFINITY,-INFINITY};
    float l_run[4] = {0.f,0.f,0.f,0.f};

    bf16x8 kr0 = *(const bf16x8*)(kstage);
    bf16x8 kr1 = *(const bf16x8*)(kstage + 8);
    bf16x8 vr0 = *(const bf16x8*)(vstage);
    bf16x8 vr1 = *(const bf16x8*)(vstage + 8);
    *(bf16x8*)&K_lds[sh][sr][sc]     = kr0;
    *(bf16x8*)&K_lds[sh][sr][sc + 8] = kr1;
    *(bf16x8*)&V_lds[sh][sr][sc]     = vr0;
    *(bf16x8*)&V_lds[sh][sr][sc + 8] = vr1;

    float sphr[4][4];
    #pragma unroll
    for (int nf = 0; nf < 4; ++nf) {
        sphr[nf][0] = sph_p0[nf*16];
        sphr[nf][1] = sph_p1[nf*16];
        sphr[nf][2] = sph_p2[nf*16];
        sphr[nf][3] = sph_p3[nf*16];
    }

    for (int kt = 0; kt < 16; ++kt) {
        __syncthreads();

        if (kt < 15) {
            const unsigned short* kp = kstage + (size_t)(kt+1)*64*DK_;
            const unsigned short* vp = vstage + (kt+1)*64;
            kr0 = *(const bf16x8*)(kp);
            kr1 = *(const bf16x8*)(kp + 8);
            vr0 = *(const bf16x8*)(vp);
            vr1 = *(const bf16x8*)(vp + 8);
        }

        f32x4 sc4[4];
        #pragma unroll
        for (int nf = 0; nf < 4; ++nf) {
            bf16x8 kf0 = *(const bf16x8*)&K_lds[wh][nf*16 + lrow][lgr*8];
            bf16x8 kf1 = *(const bf16x8*)&K_lds[wh][nf*16 + lrow][32 + lgr*8];
            f32x4 a = {};
            a = __builtin_amdgcn_mfma_f32_16x16x32_bf16(qf0, kf0, a, 0, 0, 0);
            a = __builtin_amdgcn_mfma_f32_16x16x32_bf16(qf1, kf1, a, 0, 0, 0);
            sc4[nf] = a;
        }

        float pmax[4] = {-INFINITY,-INFINITY,-INFINITY,-INFINITY};
        #pragma unroll
        for (int nf = 0; nf < 4; ++nf)
        #pragma unroll
        for (int r = 0; r < 4; ++r) {
            float s = sc4[nf][r] * 0.125f * sphr[nf][r];
            sc4[nf][r] = s;
            pmax[r] = fmaxf(pmax[r], s);
        }
        #pragma unroll
        for (int off = 1; off < 16; off <<= 1)
            #pragma unroll
            for (int r = 0; r < 4; ++r)
                pmax[r] = fmaxf(pmax[r], __shfl_xor(pmax[r], off, 64));

        float sc_old[4], psum[4] = {0.f,0.f,0.f,0.f};
        #pragma unroll
        for (int r = 0; r < 4; ++r) {
            float mn = fmaxf(m_run[r], pmax[r]);
            sc_old[r] = __expf(m_run[r] - mn);
            m_run[r] = mn;
        }
        #pragma unroll
        for (int nf = 0; nf < 4; ++nf)
        #pragma unroll
        for (int r = 0; r < 4; ++r) {
            float p = __expf(sc4[nf][r] - m_run[r]);
            sc4[nf][r] = p;
            psum[r] += p;
        }
        #pragma unroll
        for (int off = 1; off < 16; off <<= 1)
            #pragma unroll
            for (int r = 0; r < 4; ++r)
                psum[r] += __shfl_xor(psum[r], off, 64);
        #pragma unroll
        for (int r = 0; r < 4; ++r)
            l_run[r] = l_run[r] * sc_old[r] + psum[r];
        #pragma unroll
        for (int nb = 0; nb < 4; ++nb)
            #pragma unroll
            for (int r = 0; r < 4; ++r)
                acc_o[nb][r] *= sc_old[r];

        #pragma unroll
        for (int nf = 0; nf < 4; ++nf)
        #pragma unroll
        for (int r = 0; r < 4; ++r)
            P_lds[wave][lgr*4 + r][nf*16 + lrow] = f2bf(sc4[nf][r]);
        __syncthreads();

        #pragma unroll
        for (int ks2 = 0; ks2 < 2; ++ks2) {
            bf16x8 pf = *(const bf16x8*)&P_lds[wave][lrow][ks2*32 + lgr*8];
            #pragma unroll
            for (int nb = 0; nb < 4; ++nb) {
                bf16x8 vf = *(const bf16x8*)&V_lds[wh][nb*16 + lrow][ks2*32 + lgr*8];
                acc_o[nb] = __builtin_amdgcn_mfma_f32_16x16x32_bf16(pf, vf, acc_o[nb], 0, 0, 0);
            }
        }

        if (kt < 15) {
            const int off = (kt + 1) * 64;
            #pragma unroll
            for (int nf = 0; nf < 4; ++nf) {
                sphr[nf][0] = sph_p0[off + nf*16];
                sphr[nf][1] = sph_p1[off + nf*16];
                sphr[nf][2] = sph_p2[off + nf*16];
                sphr[nf][3] = sph_p3[off + nf*16];
            }
        }
        __syncthreads();

        if (kt < 15) {
            *(bf16x8*)&K_lds[sh][sr][sc]     = kr0;
            *(bf16x8*)&K_lds[sh][sr][sc + 8] = kr1;
            *(bf16x8*)&V_lds[sh][sr][sc]     = vr0;
            *(bf16x8*)&V_lds[sh][sr][sc + 8] = vr1;
        }
    }

    if (lrow == 0) {
        #pragma unroll
        for (int r = 0; r < 4; ++r) {
            m_sh[wave][lgr*4 + r] = m_run[r];
            l_sh[wave][lgr*4 + r] = l_run[r];
        }
    }
    __syncthreads();

    float scl[4], lcomb[4];
    #pragma unroll
    for (int r = 0; r < 4; ++r) {
        int row = lgr*4 + r;
        float m0 = m_sh[wq][row],     m1 = m_sh[wq + 4][row];
        float l0 = l_sh[wq][row],     l1 = l_sh[wq + 4][row];
        float mm = fmaxf(m0, m1);
        float s0 = __expf(m0 - mm),   s1 = __expf(m1 - mm);
        lcomb[r] = l0*s0 + l1*s1;
        scl[r]   = (wh == 0) ? s0 : s1;
    }
    if (wh == 1) {
        #pragma unroll
        for (int nb = 0; nb < 4; ++nb)
        #pragma unroll
        for (int r = 0; r < 4; ++r)
            O_sh[wq][lgr*4 + r][nb*16 + lrow] = acc_o[nb][r] * scl[r];
    }
    __syncthreads();
    if (wh == 0) {
        #pragma unroll
        for (int nb = 0; nb < 4; ++nb)
        #pragma unroll
        for (int r = 0; r < 4; ++r) {
            int qrow = qbase + wq*16 + lgr*4 + r;
            float o = (acc_o[nb][r]*scl[r] + O_sh[wq][lgr*4 + r][nb*16 + lrow]) / lcomb[r];
            attn_ws[((size_t)(b*S_) + qrow)*D_ + h*64 + nb*16 + lrow] = f2bf(o);
        }
    }
}

// ---------------------------------------------------------------------------
extern "C" void kernel_launch(void* const* d_in, const int* in_sizes, int n_in,
                              void* d_out, int out_size, void* d_ws, size_t ws_size,
                              hipStream_t stream) {
    (void)in_sizes; (void)n_in; (void)out_size;
    const float* query = (const float*)d_in[0];
    const float* key_  = (const float*)d_in[1];
    const float* value = (const float*)d_in[2];
    const float* sph   = (const float*)d_in[3];
    const float* Wq = (const float*)d_in[4];
    const float* bq = (const float*)d_in[5];
    const float* Wk = (const float*)d_in[6];
    const float* bk = (const float*)d_in[7];
    const float* Wv = (const float*)d_in[8];
    const float* bv = (const float*)d_in[9];
    const float* Wo = (const float*)d_in[10];
    const float* bo = (const float*)d_in[11];

    char* ws = (char*)d_ws;
    const size_t MB = 1024*1024;
    const size_t NEED = 18*MB;

    if (ws_size >= NEED) {
        // layout: [0 WB(2MB)][2 q_ws][6 k_ws][10 vT_ws][14 attn_ws]
        unsigned short* WB      = (unsigned short*)(ws);
        unsigned short* q_ws    = (unsigned short*)(ws + 2*MB);
        unsigned short* k_ws    = (unsigned short*)(ws + 6*MB);
        unsigned short* vT_ws   = (unsigned short*)(ws + 10*MB);
        unsigned short* attn_ws = (unsigned short*)(ws + 14*MB);

        cvtw_kernel<<<512, 256, 0, stream>>>(Wq, Wk, Wv, Wo, WB);
        qkv_gemm<<<dim3(192, 8), 256, 0, stream>>>(query, key_, value, WB, bq, bk, bv,
                                                   q_ws, k_ws, vT_ws);
        attn_fast<<<dim3(S_/64, B_*H_), 512, 0, stream>>>(q_ws, k_ws, vT_ws, sph, attn_ws);
        out_gemm<<<dim3(64, 8), 256, 0, stream>>>(attn_ws, WB + 3*(size_t)NW, bo, (float*)d_out);
    } else {
        // fallback (needs 16 MiB)
        const size_t SEG = (size_t)M_ * D_ * 2;
        unsigned short* q_ws    = (unsigned short*)(ws);
        unsigned short* k_ws    = (unsigned short*)(ws + SEG);
        unsigned short* vT_ws   = (unsigned short*)(ws + 2*SEG);
        unsigned short* attn_ws = (unsigned short*)(ws + 3*SEG);

        dim3 gg(M_/64, D_/64);
        gemm_old<0, 0><<<gg, 256, 0, stream>>>(query, Wq, bq, q_ws);
        gemm_old<0, 0><<<gg, 256, 0, stream>>>(key_,  Wk, bk, k_ws);
        gemm_old<0, 1><<<gg, 256, 0, stream>>>(value, Wv, bv, vT_ws);
        attn_old<<<dim3(S_/64, B_*H_), 512, 0, stream>>>(q_ws, k_ws, vT_ws, sph, attn_ws);
        gemm_old<1, 2><<<gg, 256, 0, stream>>>(attn_ws, Wo, bo, (float*)d_out);
    }
}